// Round 7
// baseline (318.336 us; speedup 1.0000x reference)
//
#include <hip/hip_runtime.h>

#define DM    512
#define NH    8
#define DH    64
#define SEQ   2048
#define PLEN  4095
#define NB    2
#define OSPLIT 2
#define JSPAN (SEQ / OSPLIT)
#define ATT_SCALE 0.125f

typedef __attribute__((ext_vector_type(8))) _Float16 half8;
typedef __attribute__((ext_vector_type(4))) float   floatx4;

// ---------------------------------------------------------------------------
// prep: z=0 cast x -> x16; z=1 cast pe -> pe16; z=2..6 transpose+cast W
// ---------------------------------------------------------------------------
__global__ __launch_bounds__(256)
void prep(const float* __restrict__ x, const float* __restrict__ pe,
          const float* __restrict__ W0, const float* __restrict__ W1,
          const float* __restrict__ W2, const float* __restrict__ W3,
          const float* __restrict__ W4,
          _Float16* __restrict__ x16, _Float16* __restrict__ pe16,
          _Float16* __restrict__ Wt)
{
    __shared__ _Float16 tile[64 * 72];
    const int z = blockIdx.z;
    const int t = threadIdx.x;

    if (z < 2) {
        const float* src = z ? pe : x;
        _Float16* dst = z ? pe16 : x16;
        const long n = z ? (long)PLEN * DM : (long)NB * SEQ * DM;
        const long i = ((long)blockIdx.x * 256 + t) * 8;
        if (i >= n) return;
        float4 f0 = *(const float4*)(src + i);
        float4 f1 = *(const float4*)(src + i + 4);
        half8 o;
        o[0] = (_Float16)f0.x; o[1] = (_Float16)f0.y;
        o[2] = (_Float16)f0.z; o[3] = (_Float16)f0.w;
        o[4] = (_Float16)f1.x; o[5] = (_Float16)f1.y;
        o[6] = (_Float16)f1.z; o[7] = (_Float16)f1.w;
        *(half8*)(dst + i) = o;
        return;
    }
    if (blockIdx.x >= 64) return;
    const int wz = z - 2;
    const float* W = (wz == 0) ? W0 : (wz == 1) ? W1 : (wz == 2) ? W2
                   : (wz == 3) ? W3 : W4;
    _Float16* dst_base = Wt + (size_t)wz * DM * DM;
    const int n0 = (blockIdx.x & 7) * 64, k0 = (blockIdx.x >> 3) * 64;
    {
        const int kr = t >> 2, nch = (t & 3) * 16;
        const float* src = W + (size_t)(k0 + kr) * DM + n0 + nch;
        float4 f0 = *(const float4*)(src + 0);
        float4 f1 = *(const float4*)(src + 4);
        float4 f2 = *(const float4*)(src + 8);
        float4 f3 = *(const float4*)(src + 12);
        _Float16* trow = &tile[kr * 72 + nch];
        trow[0]  = (_Float16)f0.x; trow[1]  = (_Float16)f0.y;
        trow[2]  = (_Float16)f0.z; trow[3]  = (_Float16)f0.w;
        trow[4]  = (_Float16)f1.x; trow[5]  = (_Float16)f1.y;
        trow[6]  = (_Float16)f1.z; trow[7]  = (_Float16)f1.w;
        trow[8]  = (_Float16)f2.x; trow[9]  = (_Float16)f2.y;
        trow[10] = (_Float16)f2.z; trow[11] = (_Float16)f2.w;
        trow[12] = (_Float16)f3.x; trow[13] = (_Float16)f3.y;
        trow[14] = (_Float16)f3.z; trow[15] = (_Float16)f3.w;
    }
    __syncthreads();
    {
        const int nr = t >> 2, kch = (t & 3) * 16;
        half8 o0, o1;
#pragma unroll
        for (int i = 0; i < 8; ++i) o0[i] = tile[(kch + i) * 72 + nr];
#pragma unroll
        for (int i = 0; i < 8; ++i) o1[i] = tile[(kch + 8 + i) * 72 + nr];
        _Float16* dst = dst_base + (size_t)(n0 + nr) * DM + k0 + kch;
        *(half8*)dst = o0;
        *(half8*)(dst + 8) = o1;
    }
}

// ---------------------------------------------------------------------------
// Fused q/k/v/p projections (unchanged from R6).
// ---------------------------------------------------------------------------
__global__ __launch_bounds__(256)
void gemm_qkvp(const _Float16* __restrict__ X, const _Float16* __restrict__ Pe,
               const _Float16* __restrict__ Wt,
               const float* __restrict__ bq, const float* __restrict__ bk,
               const float* __restrict__ bv, const float* __restrict__ bu,
               const float* __restrict__ bvb,
               _Float16* __restrict__ qu16, _Float16* __restrict__ qv16,
               _Float16* __restrict__ k16, _Float16* __restrict__ vt16,
               _Float16* __restrict__ p16)
{
    __shared__ _Float16 aS[64 * 72];
    __shared__ _Float16 wS[64 * 72];

    const int t = threadIdx.x;
    const int w = t >> 6, lane = t & 63, quad = lane >> 4, l16 = lane & 15;
    const int z = blockIdx.z;
    const int n0 = blockIdx.x * 64;
    const int m0 = blockIdx.y * 64;
    const int srow = t >> 2, sch = (t & 3) * 16;
    const _Float16* A = (z == 3) ? Pe : X;
    const _Float16* Wz = Wt + (size_t)z * DM * DM;

    floatx4 acc[4];
#pragma unroll
    for (int ct = 0; ct < 4; ++ct) acc[ct] = (floatx4){0.f, 0.f, 0.f, 0.f};

    for (int k0 = 0; k0 < DM; k0 += 64) {
        __syncthreads();
        if (z != 3 || m0 + srow < PLEN) {
            const _Float16* asrc = A + (size_t)(m0 + srow) * DM + k0 + sch;
            *(half8*)&aS[srow * 72 + sch]     = *(const half8*)asrc;
            *(half8*)&aS[srow * 72 + sch + 8] = *(const half8*)(asrc + 8);
        } else {
            half8 zz = {};
            *(half8*)&aS[srow * 72 + sch]     = zz;
            *(half8*)&aS[srow * 72 + sch + 8] = zz;
        }
        {
            const _Float16* wsrc = Wz + (size_t)(n0 + srow) * DM + k0 + sch;
            *(half8*)&wS[srow * 72 + sch]     = *(const half8*)wsrc;
            *(half8*)&wS[srow * 72 + sch + 8] = *(const half8*)(wsrc + 8);
        }
        __syncthreads();
#pragma unroll
        for (int kb = 0; kb < 2; ++kb) {
            half8 af = *(const half8*)&aS[(16 * w + l16) * 72 + kb * 32 + quad * 8];
#pragma unroll
            for (int ct = 0; ct < 4; ++ct) {
                half8 bf = *(const half8*)&wS[(16 * ct + l16) * 72 + kb * 32 + quad * 8];
                acc[ct] = __builtin_amdgcn_mfma_f32_16x16x32_f16(af, bf, acc[ct], 0, 0, 0);
            }
        }
    }

    const int h = n0 >> 6;
    if (z == 0) {
#pragma unroll
        for (int ct = 0; ct < 4; ++ct) {
            const int n = n0 + 16 * ct + l16;
            const float bval = bq[n], uval = bu[n], vval = bvb[n];
#pragma unroll
            for (int r = 0; r < 4; ++r) {
                const int m = m0 + 16 * w + 4 * quad + r;
                const int b = m >> 11, s = m & 2047;
                const size_t dst = ((size_t)((h * NB + b) * SEQ) + s) * DH + (n & 63);
                const float q = acc[ct][r] + bval;
                qu16[dst] = (_Float16)((q + uval) * ATT_SCALE);
                qv16[dst] = (_Float16)((q + vval) * ATT_SCALE);
            }
        }
    } else if (z == 1) {
#pragma unroll
        for (int ct = 0; ct < 4; ++ct) {
            const int n = n0 + 16 * ct + l16;
            const float bval = bk[n];
#pragma unroll
            for (int r = 0; r < 4; ++r) {
                const int m = m0 + 16 * w + 4 * quad + r;
                const int b = m >> 11, s = m & 2047;
                k16[((size_t)((h * NB + b) * SEQ) + s) * DH + (n & 63)] =
                    (_Float16)(acc[ct][r] + bval);
            }
        }
    } else if (z == 2) {
        __syncthreads();
#pragma unroll
        for (int ct = 0; ct < 4; ++ct) {
            const float bval = bv[n0 + 16 * ct + l16];
#pragma unroll
            for (int r = 0; r < 4; ++r)
                aS[(16 * w + 4 * quad + r) * 72 + 16 * ct + l16] =
                    (_Float16)(acc[ct][r] + bval);
        }
        __syncthreads();
        const int b = m0 >> 11, s0 = m0 & 2047;
        const int drow = t >> 2;
        half8 o0, o1;
#pragma unroll
        for (int i = 0; i < 8; ++i) o0[i] = aS[(sch + i) * 72 + drow];
#pragma unroll
        for (int i = 0; i < 8; ++i) o1[i] = aS[(sch + 8 + i) * 72 + drow];
        _Float16* dst = vt16 + ((size_t)((h * NB + b) * DH) + drow) * SEQ + s0 + sch;
        *(half8*)dst = o0;
        *(half8*)(dst + 8) = o1;
    } else {
#pragma unroll
        for (int ct = 0; ct < 4; ++ct) {
            const int n = n0 + 16 * ct + l16;
#pragma unroll
            for (int r = 0; r < 4; ++r) {
                const int m = m0 + 16 * w + 4 * quad + r;
                if (m < PLEN)
                    p16[((size_t)h * PLEN + m) * DH + (n & 63)] = (_Float16)acc[ct][r];
            }
        }
    }
}

// ---------------------------------------------------------------------------
// Wave-per-strip rel-pos attention, NO LDS staging, NO barriers.
// One 64-thread block = one wave = 16 q-rows of (b,h), one j-split half.
// All MFMA B-frags are contiguous 16B rows of head-major global arrays
// (K[s][64], P[r][64], V^T[d][S]) -> loaded directly from global (L1/L2-hot:
// all strips of an (h,b) read the same frags; working set ~12 MB < L2).
// LDS only for the rel-shift gather (tT, fp32 col-major pitch 20, i-rotate
// swizzle, b128 writes) and probs (bS, chunk^quad swizzle -> conflict-free).
// No-max softmax (logits bounded ~|1.7|); fp16 partial O + fp32 row sums are
// linear across splits, combined in gemm_final.
// ---------------------------------------------------------------------------
__global__ __launch_bounds__(64, 4)
void relattn_wave(const _Float16* __restrict__ QU,
                  const _Float16* __restrict__ QV,
                  const _Float16* __restrict__ Kp,
                  const _Float16* __restrict__ VT,
                  const _Float16* __restrict__ Pp,
                  _Float16* __restrict__ Opart, float* __restrict__ Lpart)
{
    __shared__ float    tT[80 * 20];   // 6.4 KB: [c][i'], i' = (i + 4c) & 15
    __shared__ _Float16 bS[16 * 72];   // 2.3 KB: probs [i][chunk^quad swizzle]

    const int lane = threadIdx.x;
    const int quad = lane >> 4, l16 = lane & 15;
    const int i0 = blockIdx.x * 16;
    const int h = blockIdx.y;
    const int b = blockIdx.z & 1, split = blockIdx.z >> 1;
    const size_t hb = (size_t)(h * NB + b);

    // persistent A-frags: Qu, Qv rows i0..i0+15 (2 k-blocks of 32)
    half8 qa[2], va[2];
    {
        const _Float16* qrow = QU + (hb * SEQ + i0 + l16) * DH + quad * 8;
        const _Float16* vrow = QV + (hb * SEQ + i0 + l16) * DH + quad * 8;
        qa[0] = *(const half8*)qrow;       qa[1] = *(const half8*)(qrow + 32);
        va[0] = *(const half8*)vrow;       va[1] = *(const half8*)(vrow + 32);
    }

    floatx4 O[4];
    float lsum[4] = {0.f, 0.f, 0.f, 0.f};
#pragma unroll
    for (int ct = 0; ct < 4; ++ct) O[ct] = (floatx4){0.f, 0.f, 0.f, 0.f};

    const _Float16* Kb = Kp + hb * SEQ * DH;
    const _Float16* Vb = VT + hb * DH * SEQ;
    const _Float16* Pb = Pp + (size_t)h * PLEN * DH;

    const int jbeg = split * JSPAN, jend = jbeg + JSPAN;
    for (int j0 = jbeg; j0 < jend; j0 += 64) {
        const int pbase = (SEQ - 16) + j0 - i0;   // 16-aligned window base

        // ---- T = Qv @ Pwin^T (5 tiles) and S = Qu @ K^T (4 tiles), all
        //      independent MFMAs, B-frags straight from global ----
        floatx4 Tc[5], Sc[4];
#pragma unroll
        for (int c2 = 0; c2 < 5; ++c2) Tc[c2] = (floatx4){0.f, 0.f, 0.f, 0.f};
#pragma unroll
        for (int ct = 0; ct < 4; ++ct) Sc[ct] = (floatx4){0.f, 0.f, 0.f, 0.f};
#pragma unroll
        for (int kb = 0; kb < 2; ++kb) {
#pragma unroll
            for (int c2 = 0; c2 < 5; ++c2) {
                int prow = pbase + 16 * c2 + l16;
                if (prow > PLEN - 1) prow = PLEN - 1;   // clamp (col never gathered)
                half8 bf = *(const half8*)(Pb + (size_t)prow * DH + kb * 32 + quad * 8);
                Tc[c2] = __builtin_amdgcn_mfma_f32_16x16x32_f16(va[kb], bf, Tc[c2], 0, 0, 0);
            }
#pragma unroll
            for (int ct = 0; ct < 4; ++ct) {
                half8 bf = *(const half8*)(Kb + (size_t)(j0 + 16 * ct + l16) * DH + kb * 32 + quad * 8);
                Sc[ct] = __builtin_amdgcn_mfma_f32_16x16x32_f16(qa[kb], bf, Sc[ct], 0, 0, 0);
            }
        }

        // ---- write T: col-major fp32, i-rotate swizzle, b128 per tile ----
#pragma unroll
        for (int c2 = 0; c2 < 5; ++c2) {
            const int c = 16 * c2 + l16;
            const int ibase = (4 * quad + 4 * c) & 15;   // +r stays consecutive
            *(floatx4*)&tT[20 * c + ibase] = Tc[c2];
        }
        asm volatile("" ::: "memory");

        // ---- gather rel-shift + exp + lsum ----
#pragma unroll
        for (int ct = 0; ct < 4; ++ct)
#pragma unroll
            for (int r = 0; r < 4; ++r) {
                const int il = 4 * quad + r;
                const int c = 16 * ct + l16 - il + 15;
                const float tval = tT[20 * c + ((il + 4 * c) & 15)];
                const float e = __expf(Sc[ct][r] + tval);
                Sc[ct][r] = e;
                lsum[r] += e;
            }
        asm volatile("" ::: "memory");

        // ---- probs -> bS with chunk^quad swizzle (conflict-free) ----
#pragma unroll
        for (int ct = 0; ct < 4; ++ct) {
            const int col = 16 * ct + l16;
            const int cjs = ((col >> 3) ^ quad) * 8 + (col & 7);
#pragma unroll
            for (int r = 0; r < 4; ++r)
                bS[(4 * quad + r) * 72 + cjs] = (_Float16)Sc[ct][r];
        }
        asm volatile("" ::: "memory");

        // ---- O += P @ V (A from bS, B straight from global V^T) ----
#pragma unroll
        for (int kb = 0; kb < 2; ++kb) {
            half8 af = *(const half8*)&bS[l16 * 72 + ((4 * kb + quad) ^ (l16 >> 2)) * 8];
#pragma unroll
            for (int ct = 0; ct < 4; ++ct) {
                half8 bf = *(const half8*)(Vb + (size_t)(16 * ct + l16) * SEQ + j0 + kb * 32 + quad * 8);
                O[ct] = __builtin_amdgcn_mfma_f32_16x16x32_f16(af, bf, O[ct], 0, 0, 0);
            }
        }
        asm volatile("" ::: "memory");
    }

    // ---- epilogue: reduce lsum over 16 lanes, write fp16 partial O ----
#pragma unroll
    for (int r = 0; r < 4; ++r) {
#pragma unroll
        for (int m = 1; m < 16; m <<= 1) lsum[r] += __shfl_xor(lsum[r], m);
        const int s = i0 + 4 * quad + r;
        _Float16* orow = Opart + ((size_t)(split * NB + b) * SEQ + s) * DM + h * DH;
#pragma unroll
        for (int ct = 0; ct < 4; ++ct)
            orow[16 * ct + l16] = (_Float16)O[ct][r];
        if (l16 == 0)
            Lpart[((size_t)split * NH * NB + hb) * SEQ + s] = lsum[r];
    }
}

// ---------------------------------------------------------------------------
// Final projection with fused split-combine: A = (O0+O1) * 1/(l0+l1) -> fp16,
// C = A @ Wo^T + bo (fp32 out).
// ---------------------------------------------------------------------------
__global__ __launch_bounds__(256)
void gemm_final(const _Float16* __restrict__ Opart, const float* __restrict__ Lpart,
                const _Float16* __restrict__ Wt, const float* __restrict__ bias,
                float* __restrict__ Out)
{
    __shared__ _Float16 aS[64 * 72];
    __shared__ _Float16 wS[64 * 72];
    __shared__ float invS[8][64];

    const int t = threadIdx.x;
    const int w = t >> 6, lane = t & 63, quad = lane >> 4, l16 = lane & 15;
    const int n0 = blockIdx.x * 64;
    const int m0 = blockIdx.y * 64;
    const int srow = t >> 2, sch = (t & 3) * 16;
    const int b = m0 >> 11, s0 = m0 & 2047;

#pragma unroll
    for (int i = t; i < 512; i += 256) {
        const int hh = i >> 6, rr = i & 63;
        const size_t base = ((size_t)hh * NB + b) * SEQ + s0 + rr;
        const float l = Lpart[base] + Lpart[(size_t)NH * NB * SEQ + base];
        invS[hh][rr] = 1.f / l;
    }

    floatx4 acc[4];
#pragma unroll
    for (int ct = 0; ct < 4; ++ct) acc[ct] = (floatx4){0.f, 0.f, 0.f, 0.f};

    for (int k0 = 0; k0 < DM; k0 += 64) {
        __syncthreads();
        {
            const size_t aoff = ((size_t)b * SEQ + s0 + srow) * DM + k0 + sch;
            const _Float16* a0 = Opart + aoff;
            const _Float16* a1 = Opart + (size_t)NB * SEQ * DM + aoff;
            const float inv = invS[k0 >> 6][srow];
            half8 x0 = *(const half8*)a0;
            half8 x1 = *(const half8*)(a0 + 8);
            half8 y0 = *(const half8*)a1;
            half8 y1 = *(const half8*)(a1 + 8);
            half8 o0, o1;
#pragma unroll
            for (int i = 0; i < 8; ++i)
                o0[i] = (_Float16)(((float)x0[i] + (float)y0[i]) * inv);
#pragma unroll
            for (int i = 0; i < 8; ++i)
                o1[i] = (_Float16)(((float)x1[i] + (float)y1[i]) * inv);
            *(half8*)&aS[srow * 72 + sch]     = o0;
            *(half8*)&aS[srow * 72 + sch + 8] = o1;
            const _Float16* wsrc = Wt + (size_t)(n0 + srow) * DM + k0 + sch;
            *(half8*)&wS[srow * 72 + sch]     = *(const half8*)wsrc;
            *(half8*)&wS[srow * 72 + sch + 8] = *(const half8*)(wsrc + 8);
        }
        __syncthreads();
#pragma unroll
        for (int kb = 0; kb < 2; ++kb) {
            half8 af = *(const half8*)&aS[(16 * w + l16) * 72 + kb * 32 + quad * 8];
#pragma unroll
            for (int ct = 0; ct < 4; ++ct) {
                half8 bf = *(const half8*)&wS[(16 * ct + l16) * 72 + kb * 32 + quad * 8];
                acc[ct] = __builtin_amdgcn_mfma_f32_16x16x32_f16(af, bf, acc[ct], 0, 0, 0);
            }
        }
    }

#pragma unroll
    for (int ct = 0; ct < 4; ++ct) {
        const int n = n0 + 16 * ct + l16;
        const float bval = bias[n];
#pragma unroll
        for (int r = 0; r < 4; ++r) {
            const int m = m0 + 16 * w + 4 * quad + r;
            Out[(size_t)m * DM + n] = acc[ct][r] + bval;
        }
    }
}

extern "C" void kernel_launch(void* const* d_in, const int* in_sizes, int n_in,
                              void* d_out, int out_size, void* d_ws, size_t ws_size,
                              hipStream_t stream)
{
    (void)in_sizes; (void)n_in; (void)out_size; (void)ws_size;
    const float* x   = (const float*)d_in[0];
    const float* pe  = (const float*)d_in[1];
    const float* Wq  = (const float*)d_in[2];
    const float* bq  = (const float*)d_in[3];
    const float* Wk  = (const float*)d_in[4];
    const float* bk  = (const float*)d_in[5];
    const float* Wv  = (const float*)d_in[6];
    const float* bv  = (const float*)d_in[7];
    const float* Wp  = (const float*)d_in[8];
    const float* Wo  = (const float*)d_in[9];
    const float* bo  = (const float*)d_in[10];
    const float* pbu = (const float*)d_in[11];
    const float* pbv = (const float*)d_in[12];
    float* out = (float*)d_out;

    const size_t nX  = (size_t)NB * SEQ * DM;
    const size_t nPe = (size_t)PLEN * DM;
    const size_t nW  = (size_t)DM * DM;
    const size_t nH  = (size_t)NH * NB * SEQ * DH;
    const size_t nPh = (size_t)NH * PLEN * DH;

    _Float16* x16  = (_Float16*)d_ws;
    _Float16* pe16 = x16 + nX;
    _Float16* wt   = pe16 + nPe;            // 5 x 512x512: q,k,v,p,o
    _Float16* qu16 = wt + 5 * nW;
    _Float16* qv16 = qu16 + nH;
    _Float16* k16  = qv16 + nH;
    _Float16* vt16 = k16 + nH;
    _Float16* p16  = vt16 + nH;
    _Float16* Opart = p16 + nPh + 64;       // +64 slack; 2 x NB*SEQ*DM fp16
    float* Lpart    = (float*)(Opart + (size_t)OSPLIT * NB * SEQ * DM);

    dim3 blk(256);
    prep<<<dim3(1024, 1, 7), blk, 0, stream>>>(x, pe, Wq, Wk, Wv, Wp, Wo,
                                               x16, pe16, wt);
    gemm_qkvp<<<dim3(8, 64, 4), blk, 0, stream>>>(x16, pe16, wt,
                                                  bq, bk, bv, pbu, pbv,
                                                  qu16, qv16, k16, vt16, p16);
    relattn_wave<<<dim3(SEQ / 16, NH, NB * OSPLIT), dim3(64), 0, stream>>>(
        qu16, qv16, k16, vt16, p16, Opart, Lpart);
    gemm_final<<<dim3(8, 64), blk, 0, stream>>>(Opart, Lpart, wt + 4 * nW, bo,
                                                out);
}

// Round 8
// 187.039 us; speedup vs baseline: 1.7020x; 1.7020x over previous
//
#include <hip/hip_runtime.h>

#define DM    512
#define NH    8
#define DH    64
#define SEQ   2048
#define PLEN  4095
#define NB    2
#define ATT_SCALE 0.125f

typedef __attribute__((ext_vector_type(8))) _Float16 half8;
typedef __attribute__((ext_vector_type(4))) float   floatx4;

// ---------------------------------------------------------------------------
// prep: z=0 cast x -> x16; z=1 cast pe -> pe16; z=2..6 transpose+cast W
// ---------------------------------------------------------------------------
__global__ __launch_bounds__(256)
void prep(const float* __restrict__ x, const float* __restrict__ pe,
          const float* __restrict__ W0, const float* __restrict__ W1,
          const float* __restrict__ W2, const float* __restrict__ W3,
          const float* __restrict__ W4,
          _Float16* __restrict__ x16, _Float16* __restrict__ pe16,
          _Float16* __restrict__ Wt)
{
    __shared__ _Float16 tile[64 * 72];
    const int z = blockIdx.z;
    const int t = threadIdx.x;

    if (z < 2) {
        const float* src = z ? pe : x;
        _Float16* dst = z ? pe16 : x16;
        const long n = z ? (long)PLEN * DM : (long)NB * SEQ * DM;
        const long i = ((long)blockIdx.x * 256 + t) * 8;
        if (i >= n) return;
        float4 f0 = *(const float4*)(src + i);
        float4 f1 = *(const float4*)(src + i + 4);
        half8 o;
        o[0] = (_Float16)f0.x; o[1] = (_Float16)f0.y;
        o[2] = (_Float16)f0.z; o[3] = (_Float16)f0.w;
        o[4] = (_Float16)f1.x; o[5] = (_Float16)f1.y;
        o[6] = (_Float16)f1.z; o[7] = (_Float16)f1.w;
        *(half8*)(dst + i) = o;
        return;
    }
    if (blockIdx.x >= 64) return;
    const int wz = z - 2;
    const float* W = (wz == 0) ? W0 : (wz == 1) ? W1 : (wz == 2) ? W2
                   : (wz == 3) ? W3 : W4;
    _Float16* dst_base = Wt + (size_t)wz * DM * DM;
    const int n0 = (blockIdx.x & 7) * 64, k0 = (blockIdx.x >> 3) * 64;
    {
        const int kr = t >> 2, nch = (t & 3) * 16;
        const float* src = W + (size_t)(k0 + kr) * DM + n0 + nch;
        float4 f0 = *(const float4*)(src + 0);
        float4 f1 = *(const float4*)(src + 4);
        float4 f2 = *(const float4*)(src + 8);
        float4 f3 = *(const float4*)(src + 12);
        _Float16* trow = &tile[kr * 72 + nch];
        trow[0]  = (_Float16)f0.x; trow[1]  = (_Float16)f0.y;
        trow[2]  = (_Float16)f0.z; trow[3]  = (_Float16)f0.w;
        trow[4]  = (_Float16)f1.x; trow[5]  = (_Float16)f1.y;
        trow[6]  = (_Float16)f1.z; trow[7]  = (_Float16)f1.w;
        trow[8]  = (_Float16)f2.x; trow[9]  = (_Float16)f2.y;
        trow[10] = (_Float16)f2.z; trow[11] = (_Float16)f2.w;
        trow[12] = (_Float16)f3.x; trow[13] = (_Float16)f3.y;
        trow[14] = (_Float16)f3.z; trow[15] = (_Float16)f3.w;
    }
    __syncthreads();
    {
        const int nr = t >> 2, kch = (t & 3) * 16;
        half8 o0, o1;
#pragma unroll
        for (int i = 0; i < 8; ++i) o0[i] = tile[(kch + i) * 72 + nr];
#pragma unroll
        for (int i = 0; i < 8; ++i) o1[i] = tile[(kch + 8 + i) * 72 + nr];
        _Float16* dst = dst_base + (size_t)(n0 + nr) * DM + k0 + kch;
        *(half8*)dst = o0;
        *(half8*)(dst + 8) = o1;
    }
}

// ---------------------------------------------------------------------------
// Fused q/k/v/p projections with register-prefetch pipelining.
//   z=0: qu=(xWq+bq+bu)*SCALE, qv=(xWq+bq+bv)*SCALE head-major [h][b][s][d]
//   z=1: k16 head-major   z=2: vt16 [h][b][d][s] via LDS
//   z=3: p16 [h][r][d] from pe16 (A-row clamp; stores guarded)
// LDS 18.4 KB -> 8 blocks/CU; grid 2048 -> 8/CU.
// ---------------------------------------------------------------------------
__global__ __launch_bounds__(256)
void gemm_qkvp(const _Float16* __restrict__ X, const _Float16* __restrict__ Pe,
               const _Float16* __restrict__ Wt,
               const float* __restrict__ bq, const float* __restrict__ bk,
               const float* __restrict__ bv, const float* __restrict__ bu,
               const float* __restrict__ bvb,
               _Float16* __restrict__ qu16, _Float16* __restrict__ qv16,
               _Float16* __restrict__ k16, _Float16* __restrict__ vt16,
               _Float16* __restrict__ p16)
{
    __shared__ _Float16 aS[64 * 72];
    __shared__ _Float16 wS[64 * 72];

    const int t = threadIdx.x;
    const int w = t >> 6, lane = t & 63, quad = lane >> 4, l16 = lane & 15;
    const int z = blockIdx.z;
    const int n0 = blockIdx.x * 64;
    const int m0 = blockIdx.y * 64;
    const int srow = t >> 2, sch = (t & 3) * 16;
    const _Float16* A = (z == 3) ? Pe : X;
    const _Float16* Wz = Wt + (size_t)z * DM * DM;

    int arow = m0 + srow;
    if (z == 3 && arow > PLEN - 1) arow = PLEN - 1;   // clamp; store guarded
    const _Float16* arowp = A + (size_t)arow * DM + sch;
    const _Float16* wrowp = Wz + (size_t)(n0 + srow) * DM + sch;

    floatx4 acc[4];
#pragma unroll
    for (int ct = 0; ct < 4; ++ct) acc[ct] = (floatx4){0.f, 0.f, 0.f, 0.f};

    half8 pa0 = *(const half8*)arowp;
    half8 pa1 = *(const half8*)(arowp + 8);
    half8 pw0 = *(const half8*)wrowp;
    half8 pw1 = *(const half8*)(wrowp + 8);

    for (int k0 = 0; k0 < DM; k0 += 64) {
        __syncthreads();
        *(half8*)&aS[srow * 72 + sch]     = pa0;
        *(half8*)&aS[srow * 72 + sch + 8] = pa1;
        *(half8*)&wS[srow * 72 + sch]     = pw0;
        *(half8*)&wS[srow * 72 + sch + 8] = pw1;
        __syncthreads();
        if (k0 + 64 < DM) {
            pa0 = *(const half8*)(arowp + k0 + 64);
            pa1 = *(const half8*)(arowp + k0 + 72);
            pw0 = *(const half8*)(wrowp + k0 + 64);
            pw1 = *(const half8*)(wrowp + k0 + 72);
        }
#pragma unroll
        for (int kb = 0; kb < 2; ++kb) {
            half8 af = *(const half8*)&aS[(16 * w + l16) * 72 + kb * 32 + quad * 8];
#pragma unroll
            for (int ct = 0; ct < 4; ++ct) {
                half8 bf = *(const half8*)&wS[(16 * ct + l16) * 72 + kb * 32 + quad * 8];
                acc[ct] = __builtin_amdgcn_mfma_f32_16x16x32_f16(af, bf, acc[ct], 0, 0, 0);
            }
        }
    }

    const int h = n0 >> 6;
    if (z == 0) {
#pragma unroll
        for (int ct = 0; ct < 4; ++ct) {
            const int n = n0 + 16 * ct + l16;
            const float bval = bq[n], uval = bu[n], vval = bvb[n];
#pragma unroll
            for (int r = 0; r < 4; ++r) {
                const int m = m0 + 16 * w + 4 * quad + r;
                const int b = m >> 11, s = m & 2047;
                const size_t dst = ((size_t)((h * NB + b) * SEQ) + s) * DH + (n & 63);
                const float q = acc[ct][r] + bval;
                qu16[dst] = (_Float16)((q + uval) * ATT_SCALE);
                qv16[dst] = (_Float16)((q + vval) * ATT_SCALE);
            }
        }
    } else if (z == 1) {
#pragma unroll
        for (int ct = 0; ct < 4; ++ct) {
            const int n = n0 + 16 * ct + l16;
            const float bval = bk[n];
#pragma unroll
            for (int r = 0; r < 4; ++r) {
                const int m = m0 + 16 * w + 4 * quad + r;
                const int b = m >> 11, s = m & 2047;
                k16[((size_t)((h * NB + b) * SEQ) + s) * DH + (n & 63)] =
                    (_Float16)(acc[ct][r] + bval);
            }
        }
    } else if (z == 2) {
        __syncthreads();
#pragma unroll
        for (int ct = 0; ct < 4; ++ct) {
            const float bval = bv[n0 + 16 * ct + l16];
#pragma unroll
            for (int r = 0; r < 4; ++r)
                aS[(16 * w + 4 * quad + r) * 72 + 16 * ct + l16] =
                    (_Float16)(acc[ct][r] + bval);
        }
        __syncthreads();
        const int b = m0 >> 11, s0 = m0 & 2047;
        const int drow = t >> 2;
        half8 o0, o1;
#pragma unroll
        for (int i = 0; i < 8; ++i) o0[i] = aS[(sch + i) * 72 + drow];
#pragma unroll
        for (int i = 0; i < 8; ++i) o1[i] = aS[(sch + 8 + i) * 72 + drow];
        _Float16* dst = vt16 + ((size_t)((h * NB + b) * DH) + drow) * SEQ + s0 + sch;
        *(half8*)dst = o0;
        *(half8*)(dst + 8) = o1;
    } else {
#pragma unroll
        for (int ct = 0; ct < 4; ++ct) {
            const int n = n0 + 16 * ct + l16;
#pragma unroll
            for (int r = 0; r < 4; ++r) {
                const int m = m0 + 16 * w + 4 * quad + r;
                if (m < PLEN)
                    p16[((size_t)h * PLEN + m) * DH + (n & 63)] = (_Float16)acc[ct][r];
            }
        }
    }
}

// ---------------------------------------------------------------------------
// MFMA flash attention with rel-pos, no-max softmax (logits bounded ~|1.7|;
// scale folded into qu/qv). R5 structure (LDS-staged B-frags, tS shared
// T/prob buffer, wave-private rows + compiler fences) + register-prefetch
// of next j-tile's K/V/P during compute. LDS 47 KB, grid 512 = 2 blocks/CU.
// ---------------------------------------------------------------------------
__global__ __launch_bounds__(256, 2)
void relattn_mfma(const _Float16* __restrict__ QU,
                  const _Float16* __restrict__ QV,
                  const _Float16* __restrict__ Kp,
                  const _Float16* __restrict__ VT,
                  const _Float16* __restrict__ Pp,
                  _Float16* __restrict__ Out)
{
    __shared__ _Float16 kS[64 * 72];
    __shared__ _Float16 pS[128 * 72];
    __shared__ _Float16 vS[64 * 72];
    __shared__ _Float16 tS[64 * 88];

    const int t = threadIdx.x;
    const int w = t >> 6, lane = t & 63, quad = lane >> 4, l16 = lane & 15;
    const int i0 = blockIdx.x * 64;
    const int h = blockIdx.y, b = blockIdx.z;
    const size_t hb = (size_t)(h * NB + b);
    const int cbase = 48 - 16 * w;

    half8 qa[2], va[2];
    {
        const _Float16* qrow = QU + (hb * SEQ + i0 + 16 * w + l16) * DH + quad * 8;
        const _Float16* vrow = QV + (hb * SEQ + i0 + 16 * w + l16) * DH + quad * 8;
        qa[0] = *(const half8*)qrow;       qa[1] = *(const half8*)(qrow + 32);
        va[0] = *(const half8*)vrow;       va[1] = *(const half8*)(vrow + 32);
    }

    floatx4 O[4];
    float lsum[4] = {0.f, 0.f, 0.f, 0.f};
#pragma unroll
    for (int ct = 0; ct < 4; ++ct) O[ct] = (floatx4){0.f, 0.f, 0.f, 0.f};

    const int srow = t >> 2, schunk = (t & 3) * 16;
    const int prow = t >> 1, pch = (t & 1) * 32;

    const _Float16* Kbase = Kp + hb * SEQ * DH;
    const _Float16* Vbase = VT + hb * DH * SEQ;
    const _Float16* Pbase = Pp + (size_t)h * PLEN * DH;
    const int rbase0 = (SEQ - 1) - i0 - 63;   // P window base at j0=0

    // ---- prefetch j0 = 0 ----
    half8 pk0, pk1, pv0, pv1;
    half8 pp0 = {}, pp1 = {}, pp2 = {}, pp3 = {};
    {
        const _Float16* src = Kbase + (size_t)srow * DH + schunk;
        pk0 = *(const half8*)src;
        pk1 = *(const half8*)(src + 8);
        const _Float16* vsrc = Vbase + (size_t)srow * SEQ + schunk;
        pv0 = *(const half8*)vsrc;
        pv1 = *(const half8*)(vsrc + 8);
        if (prow < 127) {
            const _Float16* psrc = Pbase + (size_t)(rbase0 + prow) * DH + pch;
            pp0 = *(const half8*)(psrc + 0);
            pp1 = *(const half8*)(psrc + 8);
            pp2 = *(const half8*)(psrc + 16);
            pp3 = *(const half8*)(psrc + 24);
        }
    }

    for (int j0 = 0; j0 < SEQ; j0 += 64) {
        __syncthreads();   // prior iteration's LDS reads complete

        // ---- store prefetched tiles ----
        *(half8*)&kS[srow * 72 + schunk]     = pk0;
        *(half8*)&kS[srow * 72 + schunk + 8] = pk1;
        *(half8*)&vS[srow * 72 + schunk]     = pv0;
        *(half8*)&vS[srow * 72 + schunk + 8] = pv1;
        if (prow < 127) {
            *(half8*)&pS[prow * 72 + pch + 0]  = pp0;
            *(half8*)&pS[prow * 72 + pch + 8]  = pp1;
            *(half8*)&pS[prow * 72 + pch + 16] = pp2;
            *(half8*)&pS[prow * 72 + pch + 24] = pp3;
        }
        __syncthreads();

        // ---- issue next tile's loads (in flight during compute) ----
        if (j0 + 64 < SEQ) {
            const _Float16* src = Kbase + (size_t)(j0 + 64 + srow) * DH + schunk;
            pk0 = *(const half8*)src;
            pk1 = *(const half8*)(src + 8);
            const _Float16* vsrc = Vbase + (size_t)srow * SEQ + j0 + 64 + schunk;
            pv0 = *(const half8*)vsrc;
            pv1 = *(const half8*)(vsrc + 8);
            if (prow < 127) {
                const _Float16* psrc = Pbase + (size_t)(rbase0 + j0 + 64 + prow) * DH + pch;
                pp0 = *(const half8*)(psrc + 0);
                pp1 = *(const half8*)(psrc + 8);
                pp2 = *(const half8*)(psrc + 16);
                pp3 = *(const half8*)(psrc + 24);
            }
        }

        // ---- phase A: T = Qv @ Pwin^T over this wave's 5 col-tiles ----
        {
            floatx4 Tacc[5];
#pragma unroll
            for (int c2 = 0; c2 < 5; ++c2) Tacc[c2] = (floatx4){0.f, 0.f, 0.f, 0.f};
#pragma unroll
            for (int kb = 0; kb < 2; ++kb) {
#pragma unroll
                for (int c2 = 0; c2 < 5; ++c2) {
                    half8 bf = *(const half8*)&pS[(cbase + 16 * c2 + l16) * 72 + kb * 32 + quad * 8];
                    Tacc[c2] = __builtin_amdgcn_mfma_f32_16x16x32_f16(va[kb], bf, Tacc[c2], 0, 0, 0);
                }
            }
#pragma unroll
            for (int c2 = 0; c2 < 5; ++c2)
#pragma unroll
                for (int r = 0; r < 4; ++r)
                    tS[(16 * w + 4 * quad + r) * 88 + 16 * c2 + l16] = (_Float16)Tacc[c2][r];
        }
        asm volatile("" ::: "memory");

        // ---- phase B: S = Qu @ K^T + gathered T; exp; accumulate lsum ----
        floatx4 Sc[4];
#pragma unroll
        for (int ct = 0; ct < 4; ++ct) Sc[ct] = (floatx4){0.f, 0.f, 0.f, 0.f};
#pragma unroll
        for (int kb = 0; kb < 2; ++kb) {
#pragma unroll
            for (int ct = 0; ct < 4; ++ct) {
                half8 bf = *(const half8*)&kS[(16 * ct + l16) * 72 + kb * 32 + quad * 8];
                Sc[ct] = __builtin_amdgcn_mfma_f32_16x16x32_f16(qa[kb], bf, Sc[ct], 0, 0, 0);
            }
        }
#pragma unroll
        for (int ct = 0; ct < 4; ++ct)
#pragma unroll
            for (int r = 0; r < 4; ++r) {
                const int il16 = 4 * quad + r;
                const int c = 16 * ct + l16 - il16 + 15;
                const float e = __expf(Sc[ct][r] +
                                       (float)tS[(16 * w + il16) * 88 + c]);
                Sc[ct][r] = e;
                lsum[r] += e;
            }
        asm volatile("" ::: "memory");

        // ---- probs overwrite tS (own rows; gather reads done) ----
#pragma unroll
        for (int ct = 0; ct < 4; ++ct)
#pragma unroll
            for (int r = 0; r < 4; ++r)
                tS[(16 * w + 4 * quad + r) * 88 + 16 * ct + l16] = (_Float16)Sc[ct][r];
        asm volatile("" ::: "memory");

        // ---- O += P @ V ----
#pragma unroll
        for (int kb = 0; kb < 2; ++kb) {
            half8 af = *(const half8*)&tS[(16 * w + l16) * 88 + kb * 32 + quad * 8];
#pragma unroll
            for (int ct = 0; ct < 4; ++ct) {
                half8 bf = *(const half8*)&vS[(16 * ct + l16) * 72 + kb * 32 + quad * 8];
                O[ct] = __builtin_amdgcn_mfma_f32_16x16x32_f16(af, bf, O[ct], 0, 0, 0);
            }
        }
        asm volatile("" ::: "memory");
    }

    // ---- epilogue: one lsum reduction, normalize, store fp16 ----
#pragma unroll
    for (int r = 0; r < 4; ++r) {
#pragma unroll
        for (int m = 1; m < 16; m <<= 1) lsum[r] += __shfl_xor(lsum[r], m);
        const float inv = 1.f / lsum[r];
        _Float16* orow = Out + (size_t)(b * SEQ + i0 + 16 * w + 4 * quad + r) * DM + h * DH;
#pragma unroll
        for (int ct = 0; ct < 4; ++ct)
            orow[16 * ct + l16] = (_Float16)(O[ct][r] * inv);
    }
}

// ---------------------------------------------------------------------------
// Final projection: C = ow16 @ Wo^T + bo (fp32 out), register-prefetch.
// ---------------------------------------------------------------------------
__global__ __launch_bounds__(256)
void gemm_out(const _Float16* __restrict__ A, const _Float16* __restrict__ Wt,
              const float* __restrict__ bias, float* __restrict__ Out)
{
    __shared__ _Float16 aS[64 * 72];
    __shared__ _Float16 wS[64 * 72];

    const int t = threadIdx.x;
    const int w = t >> 6, lane = t & 63, quad = lane >> 4, l16 = lane & 15;
    const int n0 = blockIdx.x * 64;
    const int m0 = blockIdx.y * 64;
    const int srow = t >> 2, sch = (t & 3) * 16;

    const _Float16* arowp = A + (size_t)(m0 + srow) * DM + sch;
    const _Float16* wrowp = Wt + (size_t)(n0 + srow) * DM + sch;

    floatx4 acc[4];
#pragma unroll
    for (int ct = 0; ct < 4; ++ct) acc[ct] = (floatx4){0.f, 0.f, 0.f, 0.f};

    half8 pa0 = *(const half8*)arowp;
    half8 pa1 = *(const half8*)(arowp + 8);
    half8 pw0 = *(const half8*)wrowp;
    half8 pw1 = *(const half8*)(wrowp + 8);

    for (int k0 = 0; k0 < DM; k0 += 64) {
        __syncthreads();
        *(half8*)&aS[srow * 72 + sch]     = pa0;
        *(half8*)&aS[srow * 72 + sch + 8] = pa1;
        *(half8*)&wS[srow * 72 + sch]     = pw0;
        *(half8*)&wS[srow * 72 + sch + 8] = pw1;
        __syncthreads();
        if (k0 + 64 < DM) {
            pa0 = *(const half8*)(arowp + k0 + 64);
            pa1 = *(const half8*)(arowp + k0 + 72);
            pw0 = *(const half8*)(wrowp + k0 + 64);
            pw1 = *(const half8*)(wrowp + k0 + 72);
        }
#pragma unroll
        for (int kb = 0; kb < 2; ++kb) {
            half8 af = *(const half8*)&aS[(16 * w + l16) * 72 + kb * 32 + quad * 8];
#pragma unroll
            for (int ct = 0; ct < 4; ++ct) {
                half8 bf = *(const half8*)&wS[(16 * ct + l16) * 72 + kb * 32 + quad * 8];
                acc[ct] = __builtin_amdgcn_mfma_f32_16x16x32_f16(af, bf, acc[ct], 0, 0, 0);
            }
        }
    }

#pragma unroll
    for (int ct = 0; ct < 4; ++ct) {
        const int n = n0 + 16 * ct + l16;
        const float bval = bias[n];
#pragma unroll
        for (int r = 0; r < 4; ++r) {
            const int m = m0 + 16 * w + 4 * quad + r;
            Out[(size_t)m * DM + n] = acc[ct][r] + bval;
        }
    }
}

extern "C" void kernel_launch(void* const* d_in, const int* in_sizes, int n_in,
                              void* d_out, int out_size, void* d_ws, size_t ws_size,
                              hipStream_t stream)
{
    (void)in_sizes; (void)n_in; (void)out_size; (void)ws_size;
    const float* x   = (const float*)d_in[0];
    const float* pe  = (const float*)d_in[1];
    const float* Wq  = (const float*)d_in[2];
    const float* bq  = (const float*)d_in[3];
    const float* Wk  = (const float*)d_in[4];
    const float* bk  = (const float*)d_in[5];
    const float* Wv  = (const float*)d_in[6];
    const float* bv  = (const float*)d_in[7];
    const float* Wp  = (const float*)d_in[8];
    const float* Wo  = (const float*)d_in[9];
    const float* bo  = (const float*)d_in[10];
    const float* pbu = (const float*)d_in[11];
    const float* pbv = (const float*)d_in[12];
    float* out = (float*)d_out;

    const size_t nX  = (size_t)NB * SEQ * DM;
    const size_t nPe = (size_t)PLEN * DM;
    const size_t nW  = (size_t)DM * DM;
    const size_t nH  = (size_t)NH * NB * SEQ * DH;
    const size_t nPh = (size_t)NH * PLEN * DH;

    _Float16* x16  = (_Float16*)d_ws;
    _Float16* pe16 = x16 + nX;
    _Float16* wt   = pe16 + nPe;            // 5 x 512x512: q,k,v,p,o
    _Float16* qu16 = wt + 5 * nW;
    _Float16* qv16 = qu16 + nH;
    _Float16* k16  = qv16 + nH;
    _Float16* vt16 = k16 + nH;
    _Float16* p16  = vt16 + nH;
    _Float16* ow16 = p16 + nPh;

    dim3 blk(256);
    prep<<<dim3(1024, 1, 7), blk, 0, stream>>>(x, pe, Wq, Wk, Wv, Wp, Wo,
                                               x16, pe16, wt);
    gemm_qkvp<<<dim3(8, 64, 4), blk, 0, stream>>>(x16, pe16, wt,
                                                  bq, bk, bv, pbu, pbv,
                                                  qu16, qv16, k16, vt16, p16);
    relattn_mfma<<<dim3(SEQ / 64, NH, NB), blk, 0, stream>>>(
        qu16, qv16, k16, vt16, p16, ow16);
    gemm_out<<<dim3(8, 64), blk, 0, stream>>>(ow16, wt + 4 * nW, bo, out);
}